// Round 2
// baseline (3741.069 us; speedup 1.0000x reference)
//
#include <hip/hip_runtime.h>

#define NN 50000
#define NE 1600000
#define C 64            // NOPEN == NUM_OUTPUT == 64
#define NIN 16
#define PAD 65          // LDS row stride (floats): bank stride 1 -> conflict-free
#define DTH 0.025f      // dt*H = (1.0/4)*0.1

// ---- setup: build fp32 transposes of KN1 and KNclose ----
__global__ void k_setup(const float* __restrict__ KN1,
                        const float* __restrict__ KNc,
                        float* __restrict__ KN1Tf, float* __restrict__ KNcTf) {
    for (int idx = threadIdx.x; idx < C * C; idx += blockDim.x) {
        int o = idx >> 6, i = idx & 63;
        KN1Tf[i * C + o] = KN1[idx];   // [i][o] = KN1[o][i]
        KNcTf[i * C + o] = KNc[idx];   // [i][o] = KNclose[o][i]
    }
}

// ---- degree / dinv ----
__global__ void k_deg_init(int* __restrict__ deg) {
    int n = blockIdx.x * blockDim.x + threadIdx.x;
    if (n < NN) deg[n] = 1;               // self loop
}
__global__ void k_deg_count(const int* __restrict__ jInd, int* __restrict__ deg) {
    int e = blockIdx.x * blockDim.x + threadIdx.x;
    if (e < NE) atomicAdd(&deg[jInd[e]], 1);
}
__global__ void k_dinv(const int* __restrict__ deg, float* __restrict__ dinv) {
    int n = blockIdx.x * blockDim.x + threadIdx.x;
    if (n < NN) dinv[n] = 1.0f / sqrtf((float)deg[n]);
}

// ---- opening: x[n*64+o] = relu(sum_i K1[o,i]*xn[i,n]); also zero div ----
__global__ void k_open(const float* __restrict__ xn,
                       const float* __restrict__ K1,
                       float* __restrict__ x, float* __restrict__ divb) {
    int idx = blockIdx.x * blockDim.x + threadIdx.x; // n*64+o
    if (idx >= NN * C) return;
    int n = idx >> 6, o = idx & 63;
    float acc = 0.f;
#pragma unroll
    for (int i = 0; i < NIN; i++)
        acc = fmaf(K1[o * NIN + i], xn[i * NN + n], acc);
    x[idx] = fmaxf(acc, 0.f);
    divb[idx] = 0.f;
}

// ---- edge kernel: one wave (block=64) handles 64 edges ----
__launch_bounds__(64)
__global__ void k_edge(const int* __restrict__ iInd, const int* __restrict__ jInd,
                       const float* __restrict__ dinv, const float* __restrict__ x,
                       const float* __restrict__ KN1f, const float* __restrict__ KN1Tf,
                       float* __restrict__ divb) {
    __shared__ float buf[C * PAD];
    __shared__ int sI[C];
    __shared__ int sJ[C];
    __shared__ float sW[C];

    const int lane = threadIdx.x;
    const int e = blockIdx.x * C + lane;   // 25000*64 == NE exactly
    const int ii = iInd[e];
    const int jj = jInd[e];
    const float w = dinv[ii] * dinv[jj];
    sI[lane] = ii; sJ[lane] = jj; sW[lane] = w;
    __syncthreads();

    // Phase A: gather (lane = channel). buf[t][lane] = w_t*(x[I_t]-x[J_t])[lane]
#pragma unroll 4
    for (int t = 0; t < C; t++) {
        int i2 = sI[t], j2 = sJ[t];
        float wv = sW[t];
        float g = wv * (x[i2 * C + lane] - x[j2 * C + lane]);
        buf[t * PAD + lane] = g;
    }
    __syncthreads();

    // Phase B1: z[o] = sum_i KN1[o][i]*g[i]   (lane = edge)
    float z[C];
#pragma unroll
    for (int o = 0; o < C; o++) z[o] = 0.f;
#pragma unroll 2
    for (int i = 0; i < C; i++) {
        float gi = buf[lane * PAD + i];
        const float* __restrict__ row = &KN1Tf[i * C];  // row[o] = KN1[o][i]
#pragma unroll
        for (int o = 0; o < C; o++) z[o] = fmaf(row[o], gi, z[o]);
    }
    // relu, stage back to LDS (own row only)
#pragma unroll
    for (int o = 0; o < C; o++) buf[lane * PAD + o] = fmaxf(z[o], 0.f);
    __syncthreads();

    // Phase B2: z2[o] = sum_i KN1[i][o]*zr[i]  (lane = edge)
    float z2[C];
#pragma unroll
    for (int o = 0; o < C; o++) z2[o] = 0.f;
#pragma unroll 2
    for (int i = 0; i < C; i++) {
        float zi = buf[lane * PAD + i];
        const float* __restrict__ row = &KN1f[i * C];   // row[o] = KN1[i][o]
#pragma unroll
        for (int o = 0; o < C; o++) z2[o] = fmaf(row[o], zi, z2[o]);
    }
    // val = w*z2, stage for transposed scatter
#pragma unroll
    for (int o = 0; o < C; o++) buf[lane * PAD + o] = w * z2[o];
    __syncthreads();

    // Phase C: scatter (lane = channel), contiguous 256B atomics per edge endpoint
#pragma unroll 2
    for (int t = 0; t < C; t++) {
        int i2 = sI[t], j2 = sJ[t];
        float v = buf[t * PAD + lane];
        atomicAdd(&divb[i2 * C + lane], v);
        atomicAdd(&divb[j2 * C + lane], -v);
    }
}

// ---- apply: x -= dt*H*div ; div = 0 for next layer ----
__global__ void k_apply(float* __restrict__ x, float* __restrict__ divb) {
    int idx = blockIdx.x * blockDim.x + threadIdx.x;
    if (idx < NN * C) { x[idx] = fmaf(-DTH, divb[idx], x[idx]); divb[idx] = 0.f; }
}

// ---- close + log_softmax: wave per node, lane = output channel ----
__launch_bounds__(256)
__global__ void k_close(const float* __restrict__ x, const float* __restrict__ KNcTf,
                        float* __restrict__ out) {
    __shared__ float M[C * C];
    for (int idx = threadIdx.x; idx < C * C; idx += 256) M[idx] = KNcTf[idx];
    __syncthreads();
    int wave = threadIdx.x >> 6, lane = threadIdx.x & 63;
    int n = blockIdx.x * 4 + wave;
    if (n >= NN) return;
    float xr = x[n * C + lane];
    float acc = 0.f;
    for (int i = 0; i < C; i++) {
        float xi = __shfl(xr, i, 64);
        acc = fmaf(M[i * C + lane], xi, acc);   // M[i][lane] = KNc[lane][i]
    }
    float m = acc;
#pragma unroll
    for (int off = 32; off; off >>= 1) m = fmaxf(m, __shfl_xor(m, off, 64));
    float s = expf(acc - m);
#pragma unroll
    for (int off = 32; off; off >>= 1) s += __shfl_xor(s, off, 64);
    out[n * C + lane] = acc - m - logf(s);
}

extern "C" void kernel_launch(void* const* d_in, const int* in_sizes, int n_in,
                              void* d_out, int out_size, void* d_ws, size_t ws_size,
                              hipStream_t stream) {
    (void)in_sizes; (void)n_in; (void)out_size; (void)ws_size;
    const float* xn   = (const float*)d_in[0];
    const int* iInd   = (const int*)d_in[1];
    const int* jInd   = (const int*)d_in[2];
    // d_in[3] = n_nodes scalar (fixed 50000)
    const float* K1   = (const float*)d_in[4];
    const float* KN1  = (const float*)d_in[5];
    const float* KNc  = (const float*)d_in[6];
    float* out = (float*)d_out;

    char* ws = (char*)d_ws;
    float* KN1Tf = (float*)ws;  ws += 64 * 64 * 4;          // 16 KB
    float* KNcTf = (float*)ws;  ws += 64 * 64 * 4;          // 16 KB
    int*   deg   = (int*)ws;    ws += ((NN * 4 + 255) / 256) * 256;
    float* dinv  = (float*)ws;  ws += ((NN * 4 + 255) / 256) * 256;
    float* x     = (float*)ws;  ws += (size_t)NN * C * 4;   // 12.8 MB
    float* divb  = (float*)ws;  ws += (size_t)NN * C * 4;   // 12.8 MB

    k_setup<<<1, 256, 0, stream>>>(KN1, KNc, KN1Tf, KNcTf);
    k_deg_init<<<(NN + 255) / 256, 256, 0, stream>>>(deg);
    k_deg_count<<<NE / 256, 256, 0, stream>>>(jInd, deg);
    k_dinv<<<(NN + 255) / 256, 256, 0, stream>>>(deg, dinv);
    k_open<<<(NN * C) / 256, 256, 0, stream>>>(xn, K1, x, divb);
    for (int l = 0; l < 4; l++) {
        k_edge<<<NE / C, C, 0, stream>>>(iInd, jInd, dinv, x, KN1, KN1Tf, divb);
        k_apply<<<(NN * C) / 256, 256, 0, stream>>>(x, divb);
    }
    k_close<<<(NN + 3) / 4, 256, 0, stream>>>(x, KNcTf, out);
}

// Round 3
// 2872.337 us; speedup vs baseline: 1.3024x; 1.3024x over previous
//
#include <hip/hip_runtime.h>

#define NN 50000
#define NE 1600000
#define C 64            // NOPEN == NUM_OUTPUT == 64
#define NIN 16
#define DTH 0.025f      // dt*H = (1.0/4)*0.1
#define LROW 72         // LDS row stride in f16 elements: 144B -> only 2-way (free) conflicts

typedef _Float16 f16x8 __attribute__((ext_vector_type(8)));
typedef _Float16 f16x4 __attribute__((ext_vector_type(4)));
typedef float f32x4 __attribute__((ext_vector_type(4)));

// ---- setup: f16 copies of KN1 (A-layout, row-major MxK) and KN1^T; fp32 KNclose^T ----
__global__ void k_setup(const float* __restrict__ KN1, const float* __restrict__ KNc,
                        _Float16* __restrict__ KN1h, _Float16* __restrict__ KN1Th,
                        float* __restrict__ KNcT) {
    for (int idx = threadIdx.x; idx < C * C; idx += blockDim.x) {
        int m = idx >> 6, k = idx & 63;
        KN1h[idx]        = (_Float16)KN1[idx];        // A1[m=o][k=i] = KN1[o][i]
        KN1Th[idx]       = (_Float16)KN1[k * C + m];  // A2[m=o2][k=i] = KN1[i][o2]
        KNcT[k * C + m]  = KNc[idx];                  // [i][o] = KNclose[o][i]
    }
}

// ---- degree / dinv ----
__global__ void k_deg_init(int* __restrict__ deg) {
    int n = blockIdx.x * blockDim.x + threadIdx.x;
    if (n < NN) deg[n] = 1;               // self loop
}
__global__ void k_deg_count(const int* __restrict__ jInd, int* __restrict__ deg) {
    int e = blockIdx.x * blockDim.x + threadIdx.x;
    if (e < NE) atomicAdd(&deg[jInd[e]], 1);
}
__global__ void k_dinv(const int* __restrict__ deg, float* __restrict__ dinv) {
    int n = blockIdx.x * blockDim.x + threadIdx.x;
    if (n < NN) dinv[n] = 1.0f / sqrtf((float)deg[n]);
}

// ---- opening: x[n*64+o] = relu(sum_i K1[o,i]*xn[i,n]); also zero div ----
__global__ void k_open(const float* __restrict__ xn, const float* __restrict__ K1,
                       float* __restrict__ x, float* __restrict__ divb) {
    int idx = blockIdx.x * blockDim.x + threadIdx.x; // n*64+o
    if (idx >= NN * C) return;
    int n = idx >> 6, o = idx & 63;
    float acc = 0.f;
#pragma unroll
    for (int i = 0; i < NIN; i++)
        acc = fmaf(K1[o * NIN + i], xn[i * NN + n], acc);
    x[idx] = fmaxf(acc, 0.f);
    divb[idx] = 0.f;
}

// ---- edge kernel: 4 waves/block, each wave owns one 64-edge tile (wave-private LDS, no barriers) ----
__launch_bounds__(256)
__global__ void k_edge(const int* __restrict__ iInd, const int* __restrict__ jInd,
                       const float* __restrict__ dinv, const float* __restrict__ x,
                       const _Float16* __restrict__ KN1h, const _Float16* __restrict__ KN1Th,
                       float* __restrict__ divb) {
    __shared__ _Float16 lds[4][C * LROW];   // 4 x 9216 B = 36.9 KB
    const int wv = threadIdx.x >> 6;
    const int lane = threadIdx.x & 63;
    _Float16* L = lds[wv];

    const int e = (blockIdx.x * 4 + wv) * C + lane;  // 6250*4*64 == NE exactly
    const int ii = iInd[e];
    const int jj = jInd[e];
    const float w = dinv[ii] * dinv[jj];

    // Phase A: gather. L[edge t][channel lane] = w_t*(x[I_t]-x[J_t])[lane]  (coalesced 256B loads)
#pragma unroll 4
    for (int t = 0; t < C; t++) {
        int it = __shfl(ii, t);
        int jt = __shfl(jj, t);
        float wt = __shfl(w, t);
        float g = wt * (x[it * C + lane] - x[jt * C + lane]);
        L[t * LROW + lane] = (_Float16)g;
    }

    const int col = lane & 15;        // n (edge) within 16-tile  /  m for A-frags
    const int quad = lane >> 4;       // selects k-group of 8

    // B-frags of G: lane holds B[k=ks*32+quad*8+j][n=nt*16+col], contiguous in LDS row
    f16x8 bf[8];
#pragma unroll
    for (int nt = 0; nt < 4; nt++)
#pragma unroll
        for (int ks = 0; ks < 2; ks++)
            bf[nt * 2 + ks] = *(const f16x8*)&L[(nt * 16 + col) * LROW + ks * 32 + quad * 8];

    // GEMM1: Z = KN1 * G  (64x64x64 = 32 MFMAs)
    f32x4 acc[16];
#pragma unroll
    for (int q = 0; q < 16; q++) acc[q] = (f32x4){0.f, 0.f, 0.f, 0.f};
#pragma unroll
    for (int mt = 0; mt < 4; mt++) {
        f16x8 a0 = *(const f16x8*)&KN1h[(mt * 16 + col) * C + quad * 8];        // k 0..31
        f16x8 a1 = *(const f16x8*)&KN1h[(mt * 16 + col) * C + 32 + quad * 8];   // k 32..63
#pragma unroll
        for (int nt = 0; nt < 4; nt++) {
            acc[mt * 4 + nt] = __builtin_amdgcn_mfma_f32_16x16x32_f16(a0, bf[nt * 2 + 0], acc[mt * 4 + nt], 0, 0, 0);
            acc[mt * 4 + nt] = __builtin_amdgcn_mfma_f32_16x16x32_f16(a1, bf[nt * 2 + 1], acc[mt * 4 + nt], 0, 0, 0);
        }
    }

    // relu(Z) -> LDS as Zt[edge][channel]  (C/D frag: row m = mt*16+quad*4+reg, col n = nt*16+col)
#pragma unroll
    for (int mt = 0; mt < 4; mt++)
#pragma unroll
        for (int nt = 0; nt < 4; nt++) {
            f32x4 v = acc[mt * 4 + nt];
            f16x4 h;
#pragma unroll
            for (int r = 0; r < 4; r++) h[r] = (_Float16)fmaxf(v[r], 0.f);
            *(f16x4*)&L[(nt * 16 + col) * LROW + mt * 16 + quad * 4] = h;  // 8B aligned
        }

    // B-frags of Z
#pragma unroll
    for (int nt = 0; nt < 4; nt++)
#pragma unroll
        for (int ks = 0; ks < 2; ks++)
            bf[nt * 2 + ks] = *(const f16x8*)&L[(nt * 16 + col) * LROW + ks * 32 + quad * 8];

    // GEMM2: Z2 = KN1^T * Z
#pragma unroll
    for (int q = 0; q < 16; q++) acc[q] = (f32x4){0.f, 0.f, 0.f, 0.f};
#pragma unroll
    for (int mt = 0; mt < 4; mt++) {
        f16x8 a0 = *(const f16x8*)&KN1Th[(mt * 16 + col) * C + quad * 8];
        f16x8 a1 = *(const f16x8*)&KN1Th[(mt * 16 + col) * C + 32 + quad * 8];
#pragma unroll
        for (int nt = 0; nt < 4; nt++) {
            acc[mt * 4 + nt] = __builtin_amdgcn_mfma_f32_16x16x32_f16(a0, bf[nt * 2 + 0], acc[mt * 4 + nt], 0, 0, 0);
            acc[mt * 4 + nt] = __builtin_amdgcn_mfma_f32_16x16x32_f16(a1, bf[nt * 2 + 1], acc[mt * 4 + nt], 0, 0, 0);
        }
    }

    // wz = w_e * Z2 -> LDS as Wt[edge][channel]
#pragma unroll
    for (int nt = 0; nt < 4; nt++) {
        float wc = __shfl(w, nt * 16 + col);
#pragma unroll
        for (int mt = 0; mt < 4; mt++) {
            f32x4 v = acc[mt * 4 + nt];
            f16x4 h;
#pragma unroll
            for (int r = 0; r < 4; r++) h[r] = (_Float16)(wc * v[r]);
            *(f16x4*)&L[(nt * 16 + col) * LROW + mt * 16 + quad * 4] = h;
        }
    }

    // Phase C: scatter (lane = channel), contiguous 256B native fp32 atomics
#pragma unroll 4
    for (int t = 0; t < C; t++) {
        int it = __shfl(ii, t);
        int jt = __shfl(jj, t);
        float v = (float)L[t * LROW + lane];
        unsafeAtomicAdd(&divb[it * C + lane], v);
        unsafeAtomicAdd(&divb[jt * C + lane], -v);
    }
}

// ---- apply: x -= dt*H*div ; div = 0 for next layer ----
__global__ void k_apply(float* __restrict__ x, float* __restrict__ divb) {
    int idx = blockIdx.x * blockDim.x + threadIdx.x;
    if (idx < NN * C) { x[idx] = fmaf(-DTH, divb[idx], x[idx]); divb[idx] = 0.f; }
}

// ---- close (+ fused final apply) + log_softmax: wave per node ----
__launch_bounds__(256)
__global__ void k_close(const float* __restrict__ x, const float* __restrict__ divb,
                        const float* __restrict__ KNcT, float* __restrict__ out) {
    __shared__ float M[C * C];
    for (int idx = threadIdx.x; idx < C * C; idx += 256) M[idx] = KNcT[idx];
    __syncthreads();
    int wave = threadIdx.x >> 6, lane = threadIdx.x & 63;
    int n = blockIdx.x * 4 + wave;
    if (n >= NN) return;
    float xr = fmaf(-DTH, divb[n * C + lane], x[n * C + lane]);  // fused last apply
    float acc = 0.f;
    for (int i = 0; i < C; i++) {
        float xi = __shfl(xr, i, 64);
        acc = fmaf(M[i * C + lane], xi, acc);   // M[i][lane] = KNc[lane][i]
    }
    float m = acc;
#pragma unroll
    for (int off = 32; off; off >>= 1) m = fmaxf(m, __shfl_xor(m, off, 64));
    float s = expf(acc - m);
#pragma unroll
    for (int off = 32; off; off >>= 1) s += __shfl_xor(s, off, 64);
    out[n * C + lane] = acc - m - logf(s);
}

extern "C" void kernel_launch(void* const* d_in, const int* in_sizes, int n_in,
                              void* d_out, int out_size, void* d_ws, size_t ws_size,
                              hipStream_t stream) {
    (void)in_sizes; (void)n_in; (void)out_size; (void)ws_size;
    const float* xn   = (const float*)d_in[0];
    const int* iInd   = (const int*)d_in[1];
    const int* jInd   = (const int*)d_in[2];
    // d_in[3] = n_nodes scalar (fixed 50000)
    const float* K1   = (const float*)d_in[4];
    const float* KN1  = (const float*)d_in[5];
    const float* KNc  = (const float*)d_in[6];
    float* out = (float*)d_out;

    char* ws = (char*)d_ws;
    _Float16* KN1h  = (_Float16*)ws; ws += C * C * 2;                 // 8 KB
    _Float16* KN1Th = (_Float16*)ws; ws += C * C * 2;                 // 8 KB
    float* KNcT     = (float*)ws;    ws += C * C * 4;                 // 16 KB
    int*   deg      = (int*)ws;      ws += ((NN * 4 + 255) / 256) * 256;
    float* dinv     = (float*)ws;    ws += ((NN * 4 + 255) / 256) * 256;
    float* x        = (float*)ws;    ws += (size_t)NN * C * 4;        // 12.8 MB
    float* divb     = (float*)ws;    ws += (size_t)NN * C * 4;        // 12.8 MB

    k_setup<<<1, 256, 0, stream>>>(KN1, KNc, KN1h, KN1Th, KNcT);
    k_deg_init<<<(NN + 255) / 256, 256, 0, stream>>>(deg);
    k_deg_count<<<NE / 256, 256, 0, stream>>>(jInd, deg);
    k_dinv<<<(NN + 255) / 256, 256, 0, stream>>>(deg, dinv);
    k_open<<<(NN * C) / 256, 256, 0, stream>>>(xn, K1, x, divb);
    for (int l = 0; l < 4; l++) {
        k_edge<<<NE / (4 * C), 256, 0, stream>>>(iInd, jInd, dinv, x, KN1h, KN1Th, divb);
        if (l < 3) k_apply<<<(NN * C) / 256, 256, 0, stream>>>(x, divb);
    }
    k_close<<<(NN + 3) / 4, 256, 0, stream>>>(x, divb, KNcT, out);
}

// Round 4
// 2367.118 us; speedup vs baseline: 1.5804x; 1.2134x over previous
//
#include <hip/hip_runtime.h>

#define NN 50000
#define NE 1600000
#define C 64            // NOPEN == NUM_OUTPUT == 64
#define NIN 16
#define DTH 0.025f      // dt*H = (1.0/4)*0.1
#define SCALE 512.0f    // edgeval staging scale (keeps ~6e-5 values out of f16 subnormals)
#define LROW 72         // LDS row stride in f16 elements: 144B -> only 2-way (free) conflicts

typedef _Float16 f16x8 __attribute__((ext_vector_type(8)));
typedef _Float16 f16x4 __attribute__((ext_vector_type(4)));
typedef float f32x4 __attribute__((ext_vector_type(4)));

// ---- setup: f16 copies of KN1 (A-layout) and KN1^T; fp32 KNclose^T ----
__global__ void k_setup(const float* __restrict__ KN1, const float* __restrict__ KNc,
                        _Float16* __restrict__ KN1h, _Float16* __restrict__ KN1Th,
                        float* __restrict__ KNcT) {
    for (int idx = threadIdx.x; idx < C * C; idx += blockDim.x) {
        int m = idx >> 6, k = idx & 63;
        KN1h[idx]        = (_Float16)KN1[idx];        // A1[m=o][k=i] = KN1[o][i]
        KN1Th[idx]       = (_Float16)KN1[k * C + m];  // A2[m=o2][k=i] = KN1[i][o2]
        KNcT[k * C + m]  = KNc[idx];                  // [i][o] = KNclose[o][i]
    }
}

// ---- CSR build: counts (+ j-degree for gcn norm) ----
__global__ void k_zero_cnt(int* __restrict__ cnt, int* __restrict__ degj) {
    int n = blockIdx.x * blockDim.x + threadIdx.x;
    if (n < NN) { cnt[n] = 0; degj[n] = 1; }          // self loop in degree
}
__global__ void k_count(const int* __restrict__ iInd, const int* __restrict__ jInd,
                        int* __restrict__ cnt, int* __restrict__ degj) {
    int e = blockIdx.x * blockDim.x + threadIdx.x;
    if (e < NE) {
        int i = iInd[e], j = jInd[e];
        atomicAdd(&cnt[i], 1);
        atomicAdd(&cnt[j], 1);
        atomicAdd(&degj[j], 1);
    }
}
// single-block exclusive scan over NN counts -> rowptr, cursor
__global__ void k_scan(const int* __restrict__ cnt, int* __restrict__ rowptr,
                       int* __restrict__ cursor) {
    __shared__ int tmp[1024];
    __shared__ int carry;
    int tid = threadIdx.x;
    if (tid == 0) carry = 0;
    __syncthreads();
    for (int base = 0; base < NN; base += 1024) {
        int v = (base + tid < NN) ? cnt[base + tid] : 0;
        tmp[tid] = v;
        __syncthreads();
#pragma unroll
        for (int off = 1; off < 1024; off <<= 1) {
            int a = (tid >= off) ? tmp[tid - off] : 0;
            __syncthreads();
            tmp[tid] += a;
            __syncthreads();
        }
        int excl = tmp[tid] - v + carry;
        if (base + tid < NN) { rowptr[base + tid] = excl; cursor[base + tid] = excl; }
        int tot = tmp[1023];
        __syncthreads();
        if (tid == 0) carry += tot;
        __syncthreads();
    }
    if (tid == 0) rowptr[NN] = carry;
}
__global__ void k_fill(const int* __restrict__ iInd, const int* __restrict__ jInd,
                       int* __restrict__ cursor, unsigned* __restrict__ csr) {
    int e = blockIdx.x * blockDim.x + threadIdx.x;
    if (e < NE) {
        int p = atomicAdd(&cursor[iInd[e]], 1);
        csr[p] = ((unsigned)e) << 1;                  // +wz  (i side)
        p = atomicAdd(&cursor[jInd[e]], 1);
        csr[p] = (((unsigned)e) << 1) | 1u;           // -wz  (j side)
    }
}
__global__ void k_dinv(const int* __restrict__ degj, float* __restrict__ dinv) {
    int n = blockIdx.x * blockDim.x + threadIdx.x;
    if (n < NN) dinv[n] = 1.0f / sqrtf((float)degj[n]);
}

// ---- opening: x[n*64+o] = relu(sum_i K1[o,i]*xn[i,n]) ----
__global__ void k_open(const float* __restrict__ xn, const float* __restrict__ K1,
                       float* __restrict__ x) {
    int idx = blockIdx.x * blockDim.x + threadIdx.x; // n*64+o
    if (idx >= NN * C) return;
    int n = idx >> 6, o = idx & 63;
    float acc = 0.f;
#pragma unroll
    for (int i = 0; i < NIN; i++)
        acc = fmaf(K1[o * NIN + i], xn[i * NN + n], acc);
    x[idx] = fmaxf(acc, 0.f);
}

// ---- edge kernel (CSR path): gather + 2 MFMA GEMMs + streamed f16 edgeval write ----
__launch_bounds__(256)
__global__ void k_edge2(const int* __restrict__ iInd, const int* __restrict__ jInd,
                        const float* __restrict__ dinv, const float* __restrict__ x,
                        const _Float16* __restrict__ KN1h, const _Float16* __restrict__ KN1Th,
                        _Float16* __restrict__ edgeval) {
    __shared__ _Float16 lds[4][C * LROW];
    const int wv = threadIdx.x >> 6;
    const int lane = threadIdx.x & 63;
    _Float16* L = lds[wv];

    const int tile = blockIdx.x * 4 + wv;
    const int e0 = tile * C;
    const int e = e0 + lane;
    const int ii = iInd[e];
    const int jj = jInd[e];
    const float w = dinv[ii] * dinv[jj];

    // Phase A: gather. L[edge t][channel lane] = w_t*(x[I_t]-x[J_t])[lane]
#pragma unroll 4
    for (int t = 0; t < C; t++) {
        int it = __shfl(ii, t);
        int jt = __shfl(jj, t);
        float wt = __shfl(w, t);
        L[t * LROW + lane] = (_Float16)(wt * (x[it * C + lane] - x[jt * C + lane]));
    }

    const int col = lane & 15;
    const int quad = lane >> 4;

    f16x8 bf[8];
#pragma unroll
    for (int nt = 0; nt < 4; nt++)
#pragma unroll
        for (int ks = 0; ks < 2; ks++)
            bf[nt * 2 + ks] = *(const f16x8*)&L[(nt * 16 + col) * LROW + ks * 32 + quad * 8];

    // GEMM1: Z = KN1 * G
    f32x4 acc[16];
#pragma unroll
    for (int q = 0; q < 16; q++) acc[q] = (f32x4){0.f, 0.f, 0.f, 0.f};
#pragma unroll
    for (int mt = 0; mt < 4; mt++) {
        f16x8 a0 = *(const f16x8*)&KN1h[(mt * 16 + col) * C + quad * 8];
        f16x8 a1 = *(const f16x8*)&KN1h[(mt * 16 + col) * C + 32 + quad * 8];
#pragma unroll
        for (int nt = 0; nt < 4; nt++) {
            acc[mt * 4 + nt] = __builtin_amdgcn_mfma_f32_16x16x32_f16(a0, bf[nt * 2 + 0], acc[mt * 4 + nt], 0, 0, 0);
            acc[mt * 4 + nt] = __builtin_amdgcn_mfma_f32_16x16x32_f16(a1, bf[nt * 2 + 1], acc[mt * 4 + nt], 0, 0, 0);
        }
    }

    // relu(Z) -> LDS as [edge][channel]
#pragma unroll
    for (int mt = 0; mt < 4; mt++)
#pragma unroll
        for (int nt = 0; nt < 4; nt++) {
            f32x4 v = acc[mt * 4 + nt];
            f16x4 h;
#pragma unroll
            for (int r = 0; r < 4; r++) h[r] = (_Float16)fmaxf(v[r], 0.f);
            *(f16x4*)&L[(nt * 16 + col) * LROW + mt * 16 + quad * 4] = h;
        }

#pragma unroll
    for (int nt = 0; nt < 4; nt++)
#pragma unroll
        for (int ks = 0; ks < 2; ks++)
            bf[nt * 2 + ks] = *(const f16x8*)&L[(nt * 16 + col) * LROW + ks * 32 + quad * 8];

    // GEMM2: Z2 = KN1^T * Z
#pragma unroll
    for (int q = 0; q < 16; q++) acc[q] = (f32x4){0.f, 0.f, 0.f, 0.f};
#pragma unroll
    for (int mt = 0; mt < 4; mt++) {
        f16x8 a0 = *(const f16x8*)&KN1Th[(mt * 16 + col) * C + quad * 8];
        f16x8 a1 = *(const f16x8*)&KN1Th[(mt * 16 + col) * C + 32 + quad * 8];
#pragma unroll
        for (int nt = 0; nt < 4; nt++) {
            acc[mt * 4 + nt] = __builtin_amdgcn_mfma_f32_16x16x32_f16(a0, bf[nt * 2 + 0], acc[mt * 4 + nt], 0, 0, 0);
            acc[mt * 4 + nt] = __builtin_amdgcn_mfma_f32_16x16x32_f16(a1, bf[nt * 2 + 1], acc[mt * 4 + nt], 0, 0, 0);
        }
    }

    // SCALE*w*Z2 -> LDS as [edge][channel]
#pragma unroll
    for (int nt = 0; nt < 4; nt++) {
        float wcs = __shfl(w, nt * 16 + col) * SCALE;
#pragma unroll
        for (int mt = 0; mt < 4; mt++) {
            f32x4 v = acc[mt * 4 + nt];
            f16x4 h;
#pragma unroll
            for (int r = 0; r < 4; r++) h[r] = (_Float16)(wcs * v[r]);
            *(f16x4*)&L[(nt * 16 + col) * LROW + mt * 16 + quad * 4] = h;
        }
    }

    // streamed coalesced write-out: 2 edges (256B) per iteration as dwords
    const uint32_t* Lu = (const uint32_t*)L;           // row stride LROW/2 = 36 uints
    uint32_t* evu = (uint32_t*)(edgeval + (size_t)e0 * C);
    const int half = lane >> 5;                        // which edge of the pair
    const int cp = lane & 31;                          // channel pair
#pragma unroll 8
    for (int t = 0; t < C; t += 2)
        evu[(t + half) * 32 + cp] = Lu[(t + half) * (LROW / 2) + cp];
}

// ---- gather (layers 0..2): div = sum_csr(+-wz); x -= dtH*div ----
__launch_bounds__(256)
__global__ void k_gather(const int* __restrict__ rowptr, const unsigned* __restrict__ csr,
                         const _Float16* __restrict__ edgeval, float* __restrict__ x) {
    int wv = threadIdx.x >> 6, lane = threadIdx.x & 63;
    int n = blockIdx.x * 4 + wv;
    if (n >= NN) return;
    int s = rowptr[n], eend = rowptr[n + 1];
    float acc = 0.f;
    for (int k = s; k < eend; k++) {
        unsigned u = csr[k];
        float v = (float)edgeval[(size_t)(u >> 1) * C + lane];
        acc += (u & 1) ? -v : v;
    }
    x[n * C + lane] = fmaf(-(DTH / SCALE), acc, x[n * C + lane]);
}

// ---- fused final gather + close + log_softmax ----
__launch_bounds__(256)
__global__ void k_gather_close(const int* __restrict__ rowptr, const unsigned* __restrict__ csr,
                               const _Float16* __restrict__ edgeval, const float* __restrict__ x,
                               const float* __restrict__ KNcT, float* __restrict__ out) {
    __shared__ float M[C * C];
    for (int idx = threadIdx.x; idx < C * C; idx += 256) M[idx] = KNcT[idx];
    __syncthreads();
    int wv = threadIdx.x >> 6, lane = threadIdx.x & 63;
    int n = blockIdx.x * 4 + wv;
    if (n >= NN) return;
    int s = rowptr[n], eend = rowptr[n + 1];
    float acc = 0.f;
    for (int k = s; k < eend; k++) {
        unsigned u = csr[k];
        float v = (float)edgeval[(size_t)(u >> 1) * C + lane];
        acc += (u & 1) ? -v : v;
    }
    float xr = fmaf(-(DTH / SCALE), acc, x[n * C + lane]);
    float o = 0.f;
    for (int i = 0; i < C; i++) {
        float xi = __shfl(xr, i, 64);
        o = fmaf(M[i * C + lane], xi, o);
    }
    float m = o;
#pragma unroll
    for (int off = 32; off; off >>= 1) m = fmaxf(m, __shfl_xor(m, off, 64));
    float sum = expf(o - m);
#pragma unroll
    for (int off = 32; off; off >>= 1) sum += __shfl_xor(sum, off, 64);
    out[n * C + lane] = o - m - logf(sum);
}

// ======== fallback (small ws): round-3 atomic path ========
__global__ void k_zero_div(float* __restrict__ divb) {
    int idx = blockIdx.x * blockDim.x + threadIdx.x;
    if (idx < NN * C) divb[idx] = 0.f;
}
__launch_bounds__(256)
__global__ void k_edge(const int* __restrict__ iInd, const int* __restrict__ jInd,
                       const float* __restrict__ dinv, const float* __restrict__ x,
                       const _Float16* __restrict__ KN1h, const _Float16* __restrict__ KN1Th,
                       float* __restrict__ divb) {
    __shared__ _Float16 lds[4][C * LROW];
    const int wv = threadIdx.x >> 6;
    const int lane = threadIdx.x & 63;
    _Float16* L = lds[wv];
    const int e = (blockIdx.x * 4 + wv) * C + lane;
    const int ii = iInd[e];
    const int jj = jInd[e];
    const float w = dinv[ii] * dinv[jj];
#pragma unroll 4
    for (int t = 0; t < C; t++) {
        int it = __shfl(ii, t);
        int jt = __shfl(jj, t);
        float wt = __shfl(w, t);
        L[t * LROW + lane] = (_Float16)(wt * (x[it * C + lane] - x[jt * C + lane]));
    }
    const int col = lane & 15;
    const int quad = lane >> 4;
    f16x8 bf[8];
#pragma unroll
    for (int nt = 0; nt < 4; nt++)
#pragma unroll
        for (int ks = 0; ks < 2; ks++)
            bf[nt * 2 + ks] = *(const f16x8*)&L[(nt * 16 + col) * LROW + ks * 32 + quad * 8];
    f32x4 acc[16];
#pragma unroll
    for (int q = 0; q < 16; q++) acc[q] = (f32x4){0.f, 0.f, 0.f, 0.f};
#pragma unroll
    for (int mt = 0; mt < 4; mt++) {
        f16x8 a0 = *(const f16x8*)&KN1h[(mt * 16 + col) * C + quad * 8];
        f16x8 a1 = *(const f16x8*)&KN1h[(mt * 16 + col) * C + 32 + quad * 8];
#pragma unroll
        for (int nt = 0; nt < 4; nt++) {
            acc[mt * 4 + nt] = __builtin_amdgcn_mfma_f32_16x16x32_f16(a0, bf[nt * 2 + 0], acc[mt * 4 + nt], 0, 0, 0);
            acc[mt * 4 + nt] = __builtin_amdgcn_mfma_f32_16x16x32_f16(a1, bf[nt * 2 + 1], acc[mt * 4 + nt], 0, 0, 0);
        }
    }
#pragma unroll
    for (int mt = 0; mt < 4; mt++)
#pragma unroll
        for (int nt = 0; nt < 4; nt++) {
            f32x4 v = acc[mt * 4 + nt];
            f16x4 h;
#pragma unroll
            for (int r = 0; r < 4; r++) h[r] = (_Float16)fmaxf(v[r], 0.f);
            *(f16x4*)&L[(nt * 16 + col) * LROW + mt * 16 + quad * 4] = h;
        }
#pragma unroll
    for (int nt = 0; nt < 4; nt++)
#pragma unroll
        for (int ks = 0; ks < 2; ks++)
            bf[nt * 2 + ks] = *(const f16x8*)&L[(nt * 16 + col) * LROW + ks * 32 + quad * 8];
#pragma unroll
    for (int q = 0; q < 16; q++) acc[q] = (f32x4){0.f, 0.f, 0.f, 0.f};
#pragma unroll
    for (int mt = 0; mt < 4; mt++) {
        f16x8 a0 = *(const f16x8*)&KN1Th[(mt * 16 + col) * C + quad * 8];
        f16x8 a1 = *(const f16x8*)&KN1Th[(mt * 16 + col) * C + 32 + quad * 8];
#pragma unroll
        for (int nt = 0; nt < 4; nt++) {
            acc[mt * 4 + nt] = __builtin_amdgcn_mfma_f32_16x16x32_f16(a0, bf[nt * 2 + 0], acc[mt * 4 + nt], 0, 0, 0);
            acc[mt * 4 + nt] = __builtin_amdgcn_mfma_f32_16x16x32_f16(a1, bf[nt * 2 + 1], acc[mt * 4 + nt], 0, 0, 0);
        }
    }
#pragma unroll
    for (int nt = 0; nt < 4; nt++) {
        float wc = __shfl(w, nt * 16 + col);
#pragma unroll
        for (int mt = 0; mt < 4; mt++) {
            f32x4 v = acc[mt * 4 + nt];
            f16x4 h;
#pragma unroll
            for (int r = 0; r < 4; r++) h[r] = (_Float16)(wc * v[r]);
            *(f16x4*)&L[(nt * 16 + col) * LROW + mt * 16 + quad * 4] = h;
        }
    }
#pragma unroll 4
    for (int t = 0; t < C; t++) {
        int it = __shfl(ii, t);
        int jt = __shfl(jj, t);
        float v = (float)L[t * LROW + lane];
        unsafeAtomicAdd(&divb[it * C + lane], v);
        unsafeAtomicAdd(&divb[jt * C + lane], -v);
    }
}
__global__ void k_apply(float* __restrict__ x, float* __restrict__ divb) {
    int idx = blockIdx.x * blockDim.x + threadIdx.x;
    if (idx < NN * C) { x[idx] = fmaf(-DTH, divb[idx], x[idx]); divb[idx] = 0.f; }
}
__launch_bounds__(256)
__global__ void k_close(const float* __restrict__ x, const float* __restrict__ divb,
                        const float* __restrict__ KNcT, float* __restrict__ out) {
    __shared__ float M[C * C];
    for (int idx = threadIdx.x; idx < C * C; idx += 256) M[idx] = KNcT[idx];
    __syncthreads();
    int wave = threadIdx.x >> 6, lane = threadIdx.x & 63;
    int n = blockIdx.x * 4 + wave;
    if (n >= NN) return;
    float xr = fmaf(-DTH, divb[n * C + lane], x[n * C + lane]);
    float acc = 0.f;
    for (int i = 0; i < C; i++) {
        float xi = __shfl(xr, i, 64);
        acc = fmaf(M[i * C + lane], xi, acc);
    }
    float m = acc;
#pragma unroll
    for (int off = 32; off; off >>= 1) m = fmaxf(m, __shfl_xor(m, off, 64));
    float s = expf(acc - m);
#pragma unroll
    for (int off = 32; off; off >>= 1) s += __shfl_xor(s, off, 64);
    out[n * C + lane] = acc - m - logf(s);
}

extern "C" void kernel_launch(void* const* d_in, const int* in_sizes, int n_in,
                              void* d_out, int out_size, void* d_ws, size_t ws_size,
                              hipStream_t stream) {
    (void)in_sizes; (void)n_in; (void)out_size;
    const float* xn   = (const float*)d_in[0];
    const int* iInd   = (const int*)d_in[1];
    const int* jInd   = (const int*)d_in[2];
    const float* K1   = (const float*)d_in[4];
    const float* KN1  = (const float*)d_in[5];
    const float* KNc  = (const float*)d_in[6];
    float* out = (float*)d_out;

    char* base = (char*)d_ws;
    size_t off = 0;
    auto alloc = [&](size_t bytes) { char* p = base + off; off = (off + bytes + 255) & ~(size_t)255; return p; };
    _Float16* KN1h  = (_Float16*)alloc(C * C * 2);
    _Float16* KN1Th = (_Float16*)alloc(C * C * 2);
    float* KNcT     = (float*)alloc(C * C * 4);
    int* degj       = (int*)alloc(NN * 4);
    int* cnt        = (int*)alloc(NN * 4);
    int* rowptr     = (int*)alloc((NN + 1) * 4);
    int* cursor     = (int*)alloc(NN * 4);
    float* dinv     = (float*)alloc(NN * 4);
    float* x        = (float*)alloc((size_t)NN * C * 4);
    unsigned* csr   = (unsigned*)alloc((size_t)2 * NE * 4);       // aliases divb in fallback
    size_t need_small = off;                                       // fallback footprint
    _Float16* edgeval = (_Float16*)alloc((size_t)NE * C * 2);
    size_t need_big = off;
    bool bigws = ws_size >= need_big;
    (void)need_small;

    // shared prolog
    k_setup<<<1, 256, 0, stream>>>(KN1, KNc, KN1h, KN1Th, KNcT);
    k_zero_cnt<<<(NN + 255) / 256, 256, 0, stream>>>(cnt, degj);
    k_count<<<NE / 256, 256, 0, stream>>>(iInd, jInd, cnt, degj);
    k_dinv<<<(NN + 255) / 256, 256, 0, stream>>>(degj, dinv);
    k_open<<<(NN * C) / 256, 256, 0, stream>>>(xn, K1, x);

    if (bigws) {
        k_scan<<<1, 1024, 0, stream>>>(cnt, rowptr, cursor);
        k_fill<<<NE / 256, 256, 0, stream>>>(iInd, jInd, cursor, csr);
        for (int l = 0; l < 4; l++) {
            k_edge2<<<NE / (4 * C), 256, 0, stream>>>(iInd, jInd, dinv, x, KN1h, KN1Th, edgeval);
            if (l < 3)
                k_gather<<<(NN + 3) / 4, 256, 0, stream>>>(rowptr, csr, edgeval, x);
            else
                k_gather_close<<<(NN + 3) / 4, 256, 0, stream>>>(rowptr, csr, edgeval, x, KNcT, out);
        }
    } else {
        float* divb = (float*)csr;   // alias: 2*NE*4 == NN*C*4 == 12.8 MB
        k_zero_div<<<(NN * C) / 256, 256, 0, stream>>>(divb);
        for (int l = 0; l < 4; l++) {
            k_edge<<<NE / (4 * C), 256, 0, stream>>>(iInd, jInd, dinv, x, KN1h, KN1Th, divb);
            if (l < 3) k_apply<<<(NN * C) / 256, 256, 0, stream>>>(x, divb);
        }
        k_close<<<(NN + 3) / 4, 256, 0, stream>>>(x, divb, KNcT, out);
    }
}

// Round 5
// 1684.936 us; speedup vs baseline: 2.2203x; 1.4049x over previous
//
#include <hip/hip_runtime.h>

#define NN 50000
#define NE 1600000
#define C 64            // NOPEN == NUM_OUTPUT == 64
#define NIN 16
#define DTH 0.025f      // dt*H = (1.0/4)*0.1
#define SCALE 512.0f    // edgeval staging scale (keeps ~6e-5 values out of f16 subnormals)
#define LROW 72         // LDS row stride in f16 elements: 144B -> only 2-way (free) conflicts

typedef _Float16 f16x8 __attribute__((ext_vector_type(8)));
typedef _Float16 f16x4 __attribute__((ext_vector_type(4)));
typedef float f32x4 __attribute__((ext_vector_type(4)));

union PK2 { uint32_t u; _Float16 h[2]; };

// ---- setup: f16 copies of KN1 (A-layout) and KN1^T; fp32 KNclose^T ----
__global__ void k_setup(const float* __restrict__ KN1, const float* __restrict__ KNc,
                        _Float16* __restrict__ KN1h, _Float16* __restrict__ KN1Th,
                        float* __restrict__ KNcT) {
    for (int idx = threadIdx.x; idx < C * C; idx += blockDim.x) {
        int m = idx >> 6, k = idx & 63;
        KN1h[idx]        = (_Float16)KN1[idx];        // A1[m=o][k=i] = KN1[o][i]
        KN1Th[idx]       = (_Float16)KN1[k * C + m];  // A2[m=o2][k=i] = KN1[i][o2]
        KNcT[k * C + m]  = KNc[idx];                  // [i][o] = KNclose[o][i]
    }
}

// ---- CSR build ----
__global__ void k_zero_cnt(int* __restrict__ cnt, int* __restrict__ degj) {
    int n = blockIdx.x * blockDim.x + threadIdx.x;
    if (n < NN) { cnt[n] = 0; degj[n] = 1; }          // self loop in degree
}
__global__ void k_count(const int* __restrict__ iInd, const int* __restrict__ jInd,
                        int* __restrict__ cnt, int* __restrict__ degj) {
    int e = blockIdx.x * blockDim.x + threadIdx.x;
    if (e < NE) {
        int i = iInd[e], j = jInd[e];
        atomicAdd(&cnt[i], 1);
        atomicAdd(&cnt[j], 1);
        atomicAdd(&degj[j], 1);
    }
}
// blocked single-block scan: 1024 threads x 49 nodes each
#define NPT 49
__global__ void k_scan(const int* __restrict__ cnt, int* __restrict__ rowptr,
                       int* __restrict__ cursor) {
    __shared__ int tmp[1024];
    int tid = threadIdx.x;
    int base = tid * NPT;
    int s = 0;
    for (int i = 0; i < NPT; i++) { int n = base + i; if (n < NN) s += cnt[n]; }
    tmp[tid] = s;
    __syncthreads();
    for (int off = 1; off < 1024; off <<= 1) {
        int a = (tid >= off) ? tmp[tid - off] : 0;
        __syncthreads();
        tmp[tid] += a;
        __syncthreads();
    }
    int excl = tmp[tid] - s;
    for (int i = 0; i < NPT; i++) {
        int n = base + i;
        if (n < NN) { rowptr[n] = excl; cursor[n] = excl; excl += cnt[n]; }
    }
    if (tid == 1023) rowptr[NN] = excl;   // base >= NN for tid 1023 -> excl == grand total
}
__global__ void k_fill(const int* __restrict__ iInd, const int* __restrict__ jInd,
                       int* __restrict__ cursor, unsigned* __restrict__ csr) {
    int e = blockIdx.x * blockDim.x + threadIdx.x;
    if (e < NE) {
        int p = atomicAdd(&cursor[iInd[e]], 1);
        csr[p] = ((unsigned)e) << 1;                  // +wz  (i side)
        p = atomicAdd(&cursor[jInd[e]], 1);
        csr[p] = (((unsigned)e) << 1) | 1u;           // -wz  (j side)
    }
}
__global__ void k_dinv(const int* __restrict__ degj, float* __restrict__ dinv) {
    int n = blockIdx.x * blockDim.x + threadIdx.x;
    if (n < NN) dinv[n] = 1.0f / sqrtf((float)degj[n]);
}

// ---- opening ----
__global__ void k_open(const float* __restrict__ xn, const float* __restrict__ K1,
                       float* __restrict__ x) {
    int idx = blockIdx.x * blockDim.x + threadIdx.x; // n*64+o
    if (idx >= NN * C) return;
    int n = idx >> 6, o = idx & 63;
    float acc = 0.f;
#pragma unroll
    for (int i = 0; i < NIN; i++)
        acc = fmaf(K1[o * NIN + i], xn[i * NN + n], acc);
    x[idx] = fmaxf(acc, 0.f);
}

// ---- edge kernel (CSR path): gather + 2 MFMA GEMMs + streamed f16 edgeval write ----
__launch_bounds__(256)
__global__ void k_edge2(const int* __restrict__ iInd, const int* __restrict__ jInd,
                        const float* __restrict__ dinv, const float* __restrict__ x,
                        const _Float16* __restrict__ KN1h, const _Float16* __restrict__ KN1Th,
                        _Float16* __restrict__ edgeval) {
    __shared__ _Float16 lds[4][C * LROW];
    const int wv = threadIdx.x >> 6;
    const int lane = threadIdx.x & 63;
    _Float16* L = lds[wv];

    const int tile = blockIdx.x * 4 + wv;
    const int e0 = tile * C;
    const int e = e0 + lane;
    const int ii = iInd[e];
    const int jj = jInd[e];
    const float w = dinv[ii] * dinv[jj];

    const int grp = lane >> 5;     // which edge of the pair
    const int cp = lane & 31;      // channel pair index

    // Phase A: gather, 2 edges/iter (32 lanes each, float2 per lane)
#pragma unroll 4
    for (int t = 0; t < C; t += 2) {
        int it = __shfl(ii, t + grp);
        int jt = __shfl(jj, t + grp);
        float wt = __shfl(w, t + grp);
        float2 xi = *(const float2*)&x[it * C + cp * 2];
        float2 xj = *(const float2*)&x[jt * C + cp * 2];
        PK2 pk;
        pk.h[0] = (_Float16)(wt * (xi.x - xj.x));
        pk.h[1] = (_Float16)(wt * (xi.y - xj.y));
        *(uint32_t*)&L[(t + grp) * LROW + cp * 2] = pk.u;
    }

    const int col = lane & 15;
    const int quad = lane >> 4;

    f16x8 bf[8];
#pragma unroll
    for (int nt = 0; nt < 4; nt++)
#pragma unroll
        for (int ks = 0; ks < 2; ks++)
            bf[nt * 2 + ks] = *(const f16x8*)&L[(nt * 16 + col) * LROW + ks * 32 + quad * 8];

    // GEMM1: Z = KN1 * G
    f32x4 acc[16];
#pragma unroll
    for (int q = 0; q < 16; q++) acc[q] = (f32x4){0.f, 0.f, 0.f, 0.f};
#pragma unroll
    for (int mt = 0; mt < 4; mt++) {
        f16x8 a0 = *(const f16x8*)&KN1h[(mt * 16 + col) * C + quad * 8];
        f16x8 a1 = *(const f16x8*)&KN1h[(mt * 16 + col) * C + 32 + quad * 8];
#pragma unroll
        for (int nt = 0; nt < 4; nt++) {
            acc[mt * 4 + nt] = __builtin_amdgcn_mfma_f32_16x16x32_f16(a0, bf[nt * 2 + 0], acc[mt * 4 + nt], 0, 0, 0);
            acc[mt * 4 + nt] = __builtin_amdgcn_mfma_f32_16x16x32_f16(a1, bf[nt * 2 + 1], acc[mt * 4 + nt], 0, 0, 0);
        }
    }

    // relu(Z) -> LDS as [edge][channel]
#pragma unroll
    for (int mt = 0; mt < 4; mt++)
#pragma unroll
        for (int nt = 0; nt < 4; nt++) {
            f32x4 v = acc[mt * 4 + nt];
            f16x4 h;
#pragma unroll
            for (int r = 0; r < 4; r++) h[r] = (_Float16)fmaxf(v[r], 0.f);
            *(f16x4*)&L[(nt * 16 + col) * LROW + mt * 16 + quad * 4] = h;
        }

#pragma unroll
    for (int nt = 0; nt < 4; nt++)
#pragma unroll
        for (int ks = 0; ks < 2; ks++)
            bf[nt * 2 + ks] = *(const f16x8*)&L[(nt * 16 + col) * LROW + ks * 32 + quad * 8];

    // GEMM2: Z2 = KN1^T * Z
#pragma unroll
    for (int q = 0; q < 16; q++) acc[q] = (f32x4){0.f, 0.f, 0.f, 0.f};
#pragma unroll
    for (int mt = 0; mt < 4; mt++) {
        f16x8 a0 = *(const f16x8*)&KN1Th[(mt * 16 + col) * C + quad * 8];
        f16x8 a1 = *(const f16x8*)&KN1Th[(mt * 16 + col) * C + 32 + quad * 8];
#pragma unroll
        for (int nt = 0; nt < 4; nt++) {
            acc[mt * 4 + nt] = __builtin_amdgcn_mfma_f32_16x16x32_f16(a0, bf[nt * 2 + 0], acc[mt * 4 + nt], 0, 0, 0);
            acc[mt * 4 + nt] = __builtin_amdgcn_mfma_f32_16x16x32_f16(a1, bf[nt * 2 + 1], acc[mt * 4 + nt], 0, 0, 0);
        }
    }

    // SCALE*w*Z2 -> LDS as [edge][channel]
#pragma unroll
    for (int nt = 0; nt < 4; nt++) {
        float wcs = __shfl(w, nt * 16 + col) * SCALE;
#pragma unroll
        for (int mt = 0; mt < 4; mt++) {
            f32x4 v = acc[mt * 4 + nt];
            f16x4 h;
#pragma unroll
            for (int r = 0; r < 4; r++) h[r] = (_Float16)(wcs * v[r]);
            *(f16x4*)&L[(nt * 16 + col) * LROW + mt * 16 + quad * 4] = h;
        }
    }

    // streamed coalesced write-out: 2 edges (256B) per iteration as dwords
    const uint32_t* Lu = (const uint32_t*)L;           // row stride LROW/2 = 36 uints
    uint32_t* evu = (uint32_t*)(edgeval + (size_t)e0 * C);
#pragma unroll 8
    for (int t = 0; t < C; t += 2)
        evu[(t + grp) * 32 + cp] = Lu[(t + grp) * (LROW / 2) + cp];
}

// ---- gather (layers 0..2): 4 edges/iter, f16x2 loads, combine halves with shfl_xor ----
__launch_bounds__(256)
__global__ void k_gather(const int* __restrict__ rowptr, const unsigned* __restrict__ csr,
                         const _Float16* __restrict__ edgeval, float* __restrict__ x) {
    int wv = threadIdx.x >> 6, lane = threadIdx.x & 63;
    int n = blockIdx.x * 4 + wv;
    if (n >= NN) return;
    const int grp = lane >> 5, cp = lane & 31;
    const uint32_t* evu = (const uint32_t*)edgeval;    // 32 uints per edge
    int s = rowptr[n], eend = rowptr[n + 1];
    float ax = 0.f, ay = 0.f;
    int k = s;
    for (; k + 4 <= eend; k += 4) {
        unsigned u0 = csr[k + grp];
        unsigned u1 = csr[k + 2 + grp];
        uint32_t p0 = evu[(size_t)(u0 >> 1) * 32 + cp];
        uint32_t p1 = evu[(size_t)(u1 >> 1) * 32 + cp];
        PK2 c0, c1; c0.u = p0; c1.u = p1;
        float s0 = (u0 & 1) ? -1.f : 1.f;
        float s1 = (u1 & 1) ? -1.f : 1.f;
        ax = fmaf(s0, (float)c0.h[0], ax);
        ay = fmaf(s0, (float)c0.h[1], ay);
        ax = fmaf(s1, (float)c1.h[0], ax);
        ay = fmaf(s1, (float)c1.h[1], ay);
    }
    for (; k + 2 <= eend; k += 2) {
        unsigned u0 = csr[k + grp];
        uint32_t p0 = evu[(size_t)(u0 >> 1) * 32 + cp];
        PK2 c0; c0.u = p0;
        float s0 = (u0 & 1) ? -1.f : 1.f;
        ax = fmaf(s0, (float)c0.h[0], ax);
        ay = fmaf(s0, (float)c0.h[1], ay);
    }
    if (k < eend && grp == 0) {
        unsigned u0 = csr[k];
        uint32_t p0 = evu[(size_t)(u0 >> 1) * 32 + cp];
        PK2 c0; c0.u = p0;
        float s0 = (u0 & 1) ? -1.f : 1.f;
        ax = fmaf(s0, (float)c0.h[0], ax);
        ay = fmaf(s0, (float)c0.h[1], ay);
    }
    ax += __shfl_xor(ax, 32, 64);
    ay += __shfl_xor(ay, 32, 64);
    if (lane < 32) {
        float2* px = (float2*)&x[n * C + cp * 2];
        float2 xv = *px;
        xv.x = fmaf(-(DTH / SCALE), ax, xv.x);
        xv.y = fmaf(-(DTH / SCALE), ay, xv.y);
        *px = xv;
    }
}

// ---- fused final gather + close + log_softmax ----
__launch_bounds__(256)
__global__ void k_gather_close(const int* __restrict__ rowptr, const unsigned* __restrict__ csr,
                               const _Float16* __restrict__ edgeval, const float* __restrict__ x,
                               const float* __restrict__ KNcT, float* __restrict__ out) {
    __shared__ float M[C * C];
    for (int idx = threadIdx.x; idx < C * C; idx += 256) M[idx] = KNcT[idx];
    __syncthreads();
    int wv = threadIdx.x >> 6, lane = threadIdx.x & 63;
    int n = blockIdx.x * 4 + wv;
    if (n >= NN) return;
    const int grp = lane >> 5, cp = lane & 31;
    const uint32_t* evu = (const uint32_t*)edgeval;
    int s = rowptr[n], eend = rowptr[n + 1];
    float ax = 0.f, ay = 0.f;
    int k = s;
    for (; k + 4 <= eend; k += 4) {
        unsigned u0 = csr[k + grp];
        unsigned u1 = csr[k + 2 + grp];
        uint32_t p0 = evu[(size_t)(u0 >> 1) * 32 + cp];
        uint32_t p1 = evu[(size_t)(u1 >> 1) * 32 + cp];
        PK2 c0, c1; c0.u = p0; c1.u = p1;
        float s0 = (u0 & 1) ? -1.f : 1.f;
        float s1 = (u1 & 1) ? -1.f : 1.f;
        ax = fmaf(s0, (float)c0.h[0], ax);
        ay = fmaf(s0, (float)c0.h[1], ay);
        ax = fmaf(s1, (float)c1.h[0], ax);
        ay = fmaf(s1, (float)c1.h[1], ay);
    }
    for (; k + 2 <= eend; k += 2) {
        unsigned u0 = csr[k + grp];
        uint32_t p0 = evu[(size_t)(u0 >> 1) * 32 + cp];
        PK2 c0; c0.u = p0;
        float s0 = (u0 & 1) ? -1.f : 1.f;
        ax = fmaf(s0, (float)c0.h[0], ax);
        ay = fmaf(s0, (float)c0.h[1], ay);
    }
    if (k < eend && grp == 0) {
        unsigned u0 = csr[k];
        uint32_t p0 = evu[(size_t)(u0 >> 1) * 32 + cp];
        PK2 c0; c0.u = p0;
        float s0 = (u0 & 1) ? -1.f : 1.f;
        ax = fmaf(s0, (float)c0.h[0], ax);
        ay = fmaf(s0, (float)c0.h[1], ay);
    }
    ax += __shfl_xor(ax, 32, 64);
    ay += __shfl_xor(ay, 32, 64);
    // redistribute: lane (=channel c) takes component (c&1) from pair lane c>>1
    float lowv = __shfl(ax, lane >> 1, 64);
    float highv = __shfl(ay, lane >> 1, 64);
    float accv = (lane & 1) ? highv : lowv;
    float xr = fmaf(-(DTH / SCALE), accv, x[n * C + lane]);
    float o = 0.f;
    for (int i = 0; i < C; i++) {
        float xi = __shfl(xr, i, 64);
        o = fmaf(M[i * C + lane], xi, o);
    }
    float m = o;
#pragma unroll
    for (int off = 32; off; off >>= 1) m = fmaxf(m, __shfl_xor(m, off, 64));
    float sum = expf(o - m);
#pragma unroll
    for (int off = 32; off; off >>= 1) sum += __shfl_xor(sum, off, 64);
    out[n * C + lane] = o - m - logf(sum);
}

// ======== fallback (small ws): atomic path ========
__global__ void k_zero_div(float* __restrict__ divb) {
    int idx = blockIdx.x * blockDim.x + threadIdx.x;
    if (idx < NN * C) divb[idx] = 0.f;
}
__launch_bounds__(256)
__global__ void k_edge(const int* __restrict__ iInd, const int* __restrict__ jInd,
                       const float* __restrict__ dinv, const float* __restrict__ x,
                       const _Float16* __restrict__ KN1h, const _Float16* __restrict__ KN1Th,
                       float* __restrict__ divb) {
    __shared__ _Float16 lds[4][C * LROW];
    const int wv = threadIdx.x >> 6;
    const int lane = threadIdx.x & 63;
    _Float16* L = lds[wv];
    const int e = (blockIdx.x * 4 + wv) * C + lane;
    const int ii = iInd[e];
    const int jj = jInd[e];
    const float w = dinv[ii] * dinv[jj];
#pragma unroll 4
    for (int t = 0; t < C; t++) {
        int it = __shfl(ii, t);
        int jt = __shfl(jj, t);
        float wt = __shfl(w, t);
        L[t * LROW + lane] = (_Float16)(wt * (x[it * C + lane] - x[jt * C + lane]));
    }
    const int col = lane & 15;
    const int quad = lane >> 4;
    f16x8 bf[8];
#pragma unroll
    for (int nt = 0; nt < 4; nt++)
#pragma unroll
        for (int ks = 0; ks < 2; ks++)
            bf[nt * 2 + ks] = *(const f16x8*)&L[(nt * 16 + col) * LROW + ks * 32 + quad * 8];
    f32x4 acc[16];
#pragma unroll
    for (int q = 0; q < 16; q++) acc[q] = (f32x4){0.f, 0.f, 0.f, 0.f};
#pragma unroll
    for (int mt = 0; mt < 4; mt++) {
        f16x8 a0 = *(const f16x8*)&KN1h[(mt * 16 + col) * C + quad * 8];
        f16x8 a1 = *(const f16x8*)&KN1h[(mt * 16 + col) * C + 32 + quad * 8];
#pragma unroll
        for (int nt = 0; nt < 4; nt++) {
            acc[mt * 4 + nt] = __builtin_amdgcn_mfma_f32_16x16x32_f16(a0, bf[nt * 2 + 0], acc[mt * 4 + nt], 0, 0, 0);
            acc[mt * 4 + nt] = __builtin_amdgcn_mfma_f32_16x16x32_f16(a1, bf[nt * 2 + 1], acc[mt * 4 + nt], 0, 0, 0);
        }
    }
#pragma unroll
    for (int mt = 0; mt < 4; mt++)
#pragma unroll
        for (int nt = 0; nt < 4; nt++) {
            f32x4 v = acc[mt * 4 + nt];
            f16x4 h;
#pragma unroll
            for (int r = 0; r < 4; r++) h[r] = (_Float16)fmaxf(v[r], 0.f);
            *(f16x4*)&L[(nt * 16 + col) * LROW + mt * 16 + quad * 4] = h;
        }
#pragma unroll
    for (int nt = 0; nt < 4; nt++)
#pragma unroll
        for (int ks = 0; ks < 2; ks++)
            bf[nt * 2 + ks] = *(const f16x8*)&L[(nt * 16 + col) * LROW + ks * 32 + quad * 8];
#pragma unroll
    for (int q = 0; q < 16; q++) acc[q] = (f32x4){0.f, 0.f, 0.f, 0.f};
#pragma unroll
    for (int mt = 0; mt < 4; mt++) {
        f16x8 a0 = *(const f16x8*)&KN1Th[(mt * 16 + col) * C + quad * 8];
        f16x8 a1 = *(const f16x8*)&KN1Th[(mt * 16 + col) * C + 32 + quad * 8];
#pragma unroll
        for (int nt = 0; nt < 4; nt++) {
            acc[mt * 4 + nt] = __builtin_amdgcn_mfma_f32_16x16x32_f16(a0, bf[nt * 2 + 0], acc[mt * 4 + nt], 0, 0, 0);
            acc[mt * 4 + nt] = __builtin_amdgcn_mfma_f32_16x16x32_f16(a1, bf[nt * 2 + 1], acc[mt * 4 + nt], 0, 0, 0);
        }
    }
#pragma unroll
    for (int nt = 0; nt < 4; nt++) {
        float wc = __shfl(w, nt * 16 + col);
#pragma unroll
        for (int mt = 0; mt < 4; mt++) {
            f32x4 v = acc[mt * 4 + nt];
            f16x4 h;
#pragma unroll
            for (int r = 0; r < 4; r++) h[r] = (_Float16)(wc * v[r]);
            *(f16x4*)&L[(nt * 16 + col) * LROW + mt * 16 + quad * 4] = h;
        }
    }
#pragma unroll 4
    for (int t = 0; t < C; t++) {
        int it = __shfl(ii, t);
        int jt = __shfl(jj, t);
        float v = (float)L[t * LROW + lane];
        unsafeAtomicAdd(&divb[it * C + lane], v);
        unsafeAtomicAdd(&divb[jt * C + lane], -v);
    }
}
__global__ void k_apply(float* __restrict__ x, float* __restrict__ divb) {
    int idx = blockIdx.x * blockDim.x + threadIdx.x;
    if (idx < NN * C) { x[idx] = fmaf(-DTH, divb[idx], x[idx]); divb[idx] = 0.f; }
}
__launch_bounds__(256)
__global__ void k_close(const float* __restrict__ x, const float* __restrict__ divb,
                        const float* __restrict__ KNcT, float* __restrict__ out) {
    __shared__ float M[C * C];
    for (int idx = threadIdx.x; idx < C * C; idx += 256) M[idx] = KNcT[idx];
    __syncthreads();
    int wave = threadIdx.x >> 6, lane = threadIdx.x & 63;
    int n = blockIdx.x * 4 + wave;
    if (n >= NN) return;
    float xr = fmaf(-DTH, divb[n * C + lane], x[n * C + lane]);
    float acc = 0.f;
    for (int i = 0; i < C; i++) {
        float xi = __shfl(xr, i, 64);
        acc = fmaf(M[i * C + lane], xi, acc);
    }
    float m = acc;
#pragma unroll
    for (int off = 32; off; off >>= 1) m = fmaxf(m, __shfl_xor(m, off, 64));
    float s = expf(acc - m);
#pragma unroll
    for (int off = 32; off; off >>= 1) s += __shfl_xor(s, off, 64);
    out[n * C + lane] = acc - m - logf(s);
}

extern "C" void kernel_launch(void* const* d_in, const int* in_sizes, int n_in,
                              void* d_out, int out_size, void* d_ws, size_t ws_size,
                              hipStream_t stream) {
    (void)in_sizes; (void)n_in; (void)out_size;
    const float* xn   = (const float*)d_in[0];
    const int* iInd   = (const int*)d_in[1];
    const int* jInd   = (const int*)d_in[2];
    const float* K1   = (const float*)d_in[4];
    const float* KN1  = (const float*)d_in[5];
    const float* KNc  = (const float*)d_in[6];
    float* out = (float*)d_out;

    char* base = (char*)d_ws;
    size_t off = 0;
    auto alloc = [&](size_t bytes) { char* p = base + off; off = (off + bytes + 255) & ~(size_t)255; return p; };
    _Float16* KN1h  = (_Float16*)alloc(C * C * 2);
    _Float16* KN1Th = (_Float16*)alloc(C * C * 2);
    float* KNcT     = (float*)alloc(C * C * 4);
    int* degj       = (int*)alloc(NN * 4);
    int* cnt        = (int*)alloc(NN * 4);
    int* rowptr     = (int*)alloc((NN + 1) * 4);
    int* cursor     = (int*)alloc(NN * 4);
    float* dinv     = (float*)alloc(NN * 4);
    float* x        = (float*)alloc((size_t)NN * C * 4);
    unsigned* csr   = (unsigned*)alloc((size_t)2 * NE * 4);       // aliases divb in fallback
    size_t need_small = off;                                       // fallback footprint
    _Float16* edgeval = (_Float16*)alloc((size_t)NE * C * 2);
    size_t need_big = off;
    bool bigws = ws_size >= need_big;
    (void)need_small;

    // shared prolog
    k_setup<<<1, 256, 0, stream>>>(KN1, KNc, KN1h, KN1Th, KNcT);
    k_zero_cnt<<<(NN + 255) / 256, 256, 0, stream>>>(cnt, degj);
    k_count<<<NE / 256, 256, 0, stream>>>(iInd, jInd, cnt, degj);
    k_dinv<<<(NN + 255) / 256, 256, 0, stream>>>(degj, dinv);
    k_open<<<(NN * C) / 256, 256, 0, stream>>>(xn, K1, x);

    if (bigws) {
        k_scan<<<1, 1024, 0, stream>>>(cnt, rowptr, cursor);
        k_fill<<<NE / 256, 256, 0, stream>>>(iInd, jInd, cursor, csr);
        for (int l = 0; l < 4; l++) {
            k_edge2<<<NE / (4 * C), 256, 0, stream>>>(iInd, jInd, dinv, x, KN1h, KN1Th, edgeval);
            if (l < 3)
                k_gather<<<(NN + 3) / 4, 256, 0, stream>>>(rowptr, csr, edgeval, x);
            else
                k_gather_close<<<(NN + 3) / 4, 256, 0, stream>>>(rowptr, csr, edgeval, x, KNcT, out);
        }
    } else {
        float* divb = (float*)csr;   // alias: 2*NE*4 == NN*C*4 == 12.8 MB
        k_zero_div<<<(NN * C) / 256, 256, 0, stream>>>(divb);
        for (int l = 0; l < 4; l++) {
            k_edge<<<NE / (4 * C), 256, 0, stream>>>(iInd, jInd, dinv, x, KN1h, KN1Th, divb);
            if (l < 3) k_apply<<<(NN * C) / 256, 256, 0, stream>>>(x, divb);
        }
        k_close<<<(NN + 3) / 4, 256, 0, stream>>>(x, divb, KNcT, out);
    }
}